// Round 4
// baseline (2402.175 us; speedup 1.0000x reference)
//
#include <hip/hip_runtime.h>
#include <hip/hip_fp16.h>

// CG-SENSE: B=4, C=16, H=W=384. x lives in d_out (float2 == [.,2]).
// FFT-384 four-step, wave-synchronous. Forward (DIF): fft12 -> twiddle ->
// fft32 across lanes; output reg k = X[k + 12*rev5(li)] (scrambled).
// Inverse (DIT, fft384_scr): consumes that scrambled register layout directly.
// R1: lane exchanges xor1/2/4/8 via DPP (VALU pipe); xor16 stays ds_swizzle.
// R2 post-mortem: branchless butterflies REGRESSED (latency-bound, not
// inst-count-bound) -> reverted to R1 select-style. twiddle_chain kept
// (control kernel k_col_rhs showed it neutral).
// R3: k_col_full residency fix — CTPB 256, 2 cols/thread (slot, slot+8),
// CPITCH 415 -> LDS 25.9KB -> 6 blocks/CU -> all 1536 blocks co-resident
// (was 1.5 shifts with a half-occupancy tail), 2x ILP per wave.
// tmp fp16 (__half2/complex); smaps packed to fp16 when ws_size allows.

#define Bn 4
#define Cn 16
#define Hn 384
#define Wn 384
#define NPIX (Hn*Wn)
#define NPIX2 (NPIX/2)
#define TPB 256
#define CTPB 256          // col_full block (4 waves, 8 col-slots, 2 cols/thread)
#define RTPB 512          // col_rhs block (unchanged)
#define NCOL 16
#define TOLF 1e-10f
#define NITER 10
#define RED_BLKS 72
#define GRP 4
#define CPG 4
#define RPITCH 416
#define CPITCH 415        // col_full pitch: offmap max 414; 415%32==31 -> banks spread
#define CPITCH_R 417      // col_rhs float2 pitch (unchanged)

__device__ __forceinline__ float2 cadd(float2 a, float2 b){ return make_float2(a.x+b.x, a.y+b.y); }
__device__ __forceinline__ float2 csub(float2 a, float2 b){ return make_float2(a.x-b.x, a.y-b.y); }
__device__ __forceinline__ float2 cmulf(float2 a, float2 b){
  return make_float2(a.x*b.x - a.y*b.y, a.x*b.y + a.y*b.x);
}

__device__ __forceinline__ void wave_fence(){ asm volatile("s_waitcnt lgkmcnt(0)" ::: "memory"); }

template<int IMM>
__device__ __forceinline__ float2 shx(float2 v){
  int x = __builtin_amdgcn_ds_swizzle(__float_as_int(v.x), IMM);
  int y = __builtin_amdgcn_ds_swizzle(__float_as_int(v.y), IMM);
  return make_float2(__int_as_float(x), __int_as_float(y));
}

// DPP lane exchange on the VALU pipe (no DS). CTRL: quad_perm/row_ror/mirror.
template<int CTRL>
__device__ __forceinline__ float2 dpp2(float2 v){
  int x = __builtin_amdgcn_mov_dpp(__float_as_int(v.x), CTRL, 0xF, 0xF, true);
  int y = __builtin_amdgcn_mov_dpp(__float_as_int(v.y), CTRL, 0xF, 0xF, true);
  return make_float2(__int_as_float(x), __int_as_float(y));
}
// o[l] = v[l ^ N] within the 32-lane subgroup:
__device__ __forceinline__ float2 xchg1 (float2 v){ return dpp2<0xB1>(v);  }            // quad_perm[1,0,3,2]
__device__ __forceinline__ float2 xchg2 (float2 v){ return dpp2<0x4E>(v);  }            // quad_perm[2,3,0,1]
__device__ __forceinline__ float2 xchg4 (float2 v){ return dpp2<0x1B>(dpp2<0x141>(v)); }// xor7 then xor3
__device__ __forceinline__ float2 xchg8 (float2 v){ return dpp2<0x128>(v); }            // row_ror:8
__device__ __forceinline__ float2 xchg16(float2 v){ return shx<0x401F>(v); }            // crosses DPP row: DS

__device__ __forceinline__ int rev5(int x){
  return ((x&1)<<4) | ((x&2)<<2) | (x&4) | ((x&8)>>2) | ((x&16)>>4);
}

__device__ __forceinline__ int offmap(int w){ return w + ((w*683)>>13); }  // w + w/12, w<384

// ---- in-register FFT-12 (natural in, natural out), kernel w12^(DIR*j*k) ----
template<int DIR>
__device__ __forceinline__ void fft12(float2* v)
{
  const float S3 = (DIR<0) ? -0.86602540378443864676f : 0.86602540378443864676f;
  const float sg = (DIR<0) ? -1.f : 1.f;
  float2 t[4][3];
#pragma unroll
  for (int b = 0; b < 4; ++b) {
    float2 a0 = v[b], a1 = v[4+b], a2 = v[8+b];
    float2 s = cadd(a1,a2), d = csub(a1,a2);
    float2 mm = make_float2(a0.x - 0.5f*s.x, a0.y - 0.5f*s.y);
    float2 e  = make_float2(-d.y*S3, d.x*S3);
    t[b][0] = cadd(a0,s);
    t[b][1] = cadd(mm,e);
    t[b][2] = csub(mm,e);
  }
  const float2 w1  = make_float2(0.86602540378443864676f, sg*0.5f);
  const float2 w2  = make_float2(0.5f, sg*0.86602540378443864676f);
  const float2 w3  = make_float2(0.f, sg);
  const float2 w4t = make_float2(-0.5f, sg*0.86602540378443864676f);
  const float2 w6  = make_float2(-1.f, 0.f);
  t[1][1] = cmulf(t[1][1], w1);  t[1][2] = cmulf(t[1][2], w2);
  t[2][1] = cmulf(t[2][1], w2);  t[2][2] = cmulf(t[2][2], w4t);
  t[3][1] = cmulf(t[3][1], w3);  t[3][2] = cmulf(t[3][2], w6);
#pragma unroll
  for (int c = 0; c < 3; ++c) {
    float2 e = cadd(t[0][c], t[2][c]);
    float2 f = csub(t[0][c], t[2][c]);
    float2 g = cadd(t[1][c], t[3][c]);
    float2 h = csub(t[1][c], t[3][c]);
    float2 ih = (DIR<0) ? make_float2(h.y, -h.x) : make_float2(-h.y, h.x);
    v[c]   = cadd(e,g);
    v[c+3] = cadd(f,ih);
    v[c+6] = csub(e,g);
    v[c+9] = csub(f,ih);
  }
}

// ---- DIF FFT-32 across lanes: natural lane in, bit-reversed lane out ----
// (R1 select-style bodies — measured best; R2 branchless regressed.)
template<int DIR>
__device__ __forceinline__ void fft32_lanes(float2* v, int li)
{
  const float c2pi = (DIR<0) ? -6.2831853071795864769f : 6.2831853071795864769f;
  const float sg   = (DIR<0) ? -1.f : 1.f;
  float s, c;
  __sincosf(c2pi*(1.f/32.f)*(float)(li&15), &s, &c); float2 wA = make_float2(c,s);
  __sincosf(c2pi*(1.f/16.f)*(float)(li&7),  &s, &c); float2 wB = make_float2(c,s);
  __sincosf(c2pi*(1.f/ 8.f)*(float)(li&3),  &s, &c); float2 wC = make_float2(c,s);
  bool bA = li & 16, bB = li & 8, bC = li & 4, bD = li & 2, bE = li & 1;
#pragma unroll
  for (int k = 0; k < 12; ++k) {
    float2 a = v[k], o;
    o = xchg16(a); a = bA ? cmulf(csub(o,a), wA) : cadd(a,o);
    o = xchg8 (a); a = bB ? cmulf(csub(o,a), wB) : cadd(a,o);
    o = xchg4 (a); a = bC ? cmulf(csub(o,a), wC) : cadd(a,o);
    o = xchg2 (a);
    { float2 su = cadd(a,o), d = csub(o,a);
      float2 dw = bE ? make_float2(-sg*d.y, sg*d.x) : d;
      a = bD ? dw : su; }
    o = xchg1 (a); a = bE ? csub(o,a) : cadd(a,o);
    v[k] = a;
  }
}

// ---- DIT FFT-32 across lanes: bit-reversed lane in, natural lane out ----
// Transposed network of fft32_lanes: stages reversed, pre-twiddle on hi lanes.
template<int DIR>
__device__ __forceinline__ void fft32_lanes_dit(float2* v, int li)
{
  const float c2pi = (DIR<0) ? -6.2831853071795864769f : 6.2831853071795864769f;
  const float sg   = (DIR<0) ? -1.f : 1.f;
  float s, c;
  __sincosf(c2pi*(1.f/32.f)*(float)(li&15), &s, &c); float2 wA = make_float2(c,s);
  __sincosf(c2pi*(1.f/16.f)*(float)(li&7),  &s, &c); float2 wB = make_float2(c,s);
  __sincosf(c2pi*(1.f/ 8.f)*(float)(li&3),  &s, &c); float2 wC = make_float2(c,s);
  bool bA = li & 16, bB = li & 8, bC = li & 4, bD = li & 2, bE = li & 1;
#pragma unroll
  for (int k = 0; k < 12; ++k) {
    float2 a = v[k], o;
    // E' (xor1), no twiddle
    o = xchg1(a); a = bE ? csub(o,a) : cadd(a,o);
    // D' (xor2), pre-twiddle w4^(li&1) on hi lanes
    { float2 aw = make_float2(-sg*a.y, sg*a.x);      // i*a (sg=+1)
      a = (bD && bE) ? aw : a;
      o = xchg2(a); a = bD ? csub(o,a) : cadd(a,o); }
    // C' (xor4)
    { float2 aw = cmulf(a, wC); a = bC ? aw : a;
      o = xchg4(a); a = bC ? csub(o,a) : cadd(a,o); }
    // B' (xor8)
    { float2 aw = cmulf(a, wB); a = bB ? aw : a;
      o = xchg8(a); a = bB ? csub(o,a) : cadd(a,o); }
    // A' (xor16)
    { float2 aw = cmulf(a, wA); a = bA ? aw : a;
      o = xchg16(a); a = bA ? csub(o,a) : cadd(a,o); }
    v[k] = a;
  }
}

// Twiddle powers W^k (k=1..11) via depth-4 addition chain, applied to v[k].
__device__ __forceinline__ void twiddle_chain(float2* v, float2 W1)
{
  v[1] = cmulf(v[1], W1);
  float2 W2 = cmulf(W1,W1); v[2] = cmulf(v[2], W2);
  float2 W3 = cmulf(W2,W1); v[3] = cmulf(v[3], W3);
  float2 W4 = cmulf(W2,W2); v[4] = cmulf(v[4], W4);
  float2 W5 = cmulf(W3,W2); v[5] = cmulf(v[5], W5);
  float2 W6 = cmulf(W3,W3); v[6] = cmulf(v[6], W6);
  float2 W7 = cmulf(W4,W3); v[7] = cmulf(v[7], W7);
  float2 W8 = cmulf(W4,W4); v[8] = cmulf(v[8], W8);
  v[9]  = cmulf(v[9],  cmulf(W5,W4));
  v[10] = cmulf(v[10], cmulf(W5,W5));
  v[11] = cmulf(v[11], cmulf(W6,W5));
}

// Forward: in reg k = x[32k+li]. Out reg k1 = X[k1 + 12*rev5(li)].
template<int DIR>
__device__ __forceinline__ void fft384(float2* v, int li)
{
  fft12<DIR>(v);
  const float c2pi = (DIR<0) ? -6.2831853071795864769f : 6.2831853071795864769f;
  float s, c;
  __sincosf(c2pi*(1.f/384.f)*(float)li, &s, &c);
  twiddle_chain(v, make_float2(c,s));
  fft32_lanes<DIR>(v, li);
}

// Scrambled-input transform: in reg k = X[k + 12*rev5(li)]. Out reg k = x[32k+li].
template<int DIR>
__device__ __forceinline__ void fft384_scr(float2* v, int li)
{
  fft32_lanes_dit<DIR>(v, li);
  const float c2pi = (DIR<0) ? -6.2831853071795864769f : 6.2831853071795864769f;
  float s, c;
  __sincosf(c2pi*(1.f/384.f)*(float)li, &s, &c);
  twiddle_chain(v, make_float2(c,s));
  fft12<DIR>(v);
}

// ---------------- FFT kernels ----------------

// tmp[b,c,h,wa] = scrambled-w FFT_w(S*p). NO LDS (except xor16 swizzles).
template<bool HS>
__global__ __launch_bounds__(TPB) void k_row_fwd(
    const float2* __restrict__ p, const float* __restrict__ Sre,
    const float* __restrict__ Sim, const __half2* __restrict__ Sh,
    __half2* __restrict__ tmp)
{
  int tid = threadIdx.x;
  int wave = tid>>6, lane = tid&63, sub = lane>>5, li = lane&31;
  int row = wave*2 + sub;
  int tile = blockIdx.x % (Hn/8);
  int bc   = blockIdx.x / (Hn/8);
  int b = bc / Cn;
  int h = tile*8 + row;
  size_t gbase = (size_t)bc*NPIX + (size_t)h*Wn;
  size_t pbase = (size_t)b*NPIX + (size_t)h*Wn;

  float2 v[12];
#pragma unroll
  for (int k = 0; k < 12; ++k) {
    int w = 32*k + li;
    float2 pv = p[pbase + w];
    float sr, si;
    if (HS) { float2 sv = __half22float2(Sh[gbase + w]); sr = sv.x; si = sv.y; }
    else    { sr = Sre[gbase + w]; si = Sim[gbase + w]; }
    v[k] = make_float2(sr*pv.x - si*pv.y, sr*pv.y + si*pv.x);
  }
  fft384<-1>(v, li);
#pragma unroll
  for (int k = 0; k < 12; ++k)
    tmp[gbase + 32*k + li] = __float22half2_rn(v[k]);
}

// Iteration path: scrambled tmp -> DIT inverse -> conj(S) acc.
template<bool HS>
__global__ __launch_bounds__(TPB) void k_row_inv_scr(
    const __half2* __restrict__ tmp, const float* __restrict__ Sre,
    const float* __restrict__ Sim, const __half2* __restrict__ Sh,
    float2* __restrict__ partial)
{
  int tid = threadIdx.x;
  int wave = tid>>6, lane = tid&63, sub = lane>>5, li = lane&31;
  int row = wave*2 + sub;
  int tile = blockIdx.x % (Hn/8);
  int rest = blockIdx.x / (Hn/8);
  int g = rest % GRP;
  int b = rest / GRP;
  int h = tile*8 + row;

  size_t gbase0 = ((size_t)b*Cn + g*CPG)*NPIX + (size_t)h*Wn;
  __half2 hb[12];
#pragma unroll
  for (int k = 0; k < 12; ++k) hb[k] = tmp[gbase0 + 32*k + li];

  float2 acc[12];
#pragma unroll
  for (int k = 0; k < 12; ++k) acc[k] = make_float2(0.f, 0.f);

  for (int j = 0; j < CPG; ++j) {
    size_t gb = gbase0 + (size_t)j*NPIX;
    float2 vc[12];
#pragma unroll
    for (int k = 0; k < 12; ++k) vc[k] = __half22float2(hb[k]);
    if (j + 1 < CPG) {
      size_t gbn = gb + NPIX;
#pragma unroll
      for (int k = 0; k < 12; ++k) hb[k] = tmp[gbn + 32*k + li];
    }
    fft384_scr<1>(vc, li);            // natural-w registers
#pragma unroll
    for (int k = 0; k < 12; ++k) {
      int w = 32*k + li;
      float sr, si;
      if (HS) { float2 sv = __half22float2(Sh[gb + w]); sr = sv.x; si = sv.y; }
      else    { sr = Sre[gb + w]; si = Sim[gb + w]; }
      acc[k].x += sr*vc[k].x + si*vc[k].y;
      acc[k].y += sr*vc[k].y - si*vc[k].x;
    }
  }
  size_t pbase = ((size_t)g*Bn + b)*NPIX + (size_t)h*Wn;
#pragma unroll
  for (int k = 0; k < 12; ++k) partial[pbase + 32*k + li] = acc[k];
}

// rhs path (natural tmp from k_col_rhs), runs once: old LDS-unscramble variant.
__global__ __launch_bounds__(TPB) void k_row_inv_nat(
    const __half2* __restrict__ tmp, const float* __restrict__ Sre,
    const float* __restrict__ Sim, float2* __restrict__ partial)
{
  __shared__ float2 lbuf[8*RPITCH];
  int tid = threadIdx.x;
  int wave = tid>>6, lane = tid&63, sub = lane>>5, li = lane&31;
  int row = wave*2 + sub;
  int tile = blockIdx.x % (Hn/8);
  int rest = blockIdx.x / (Hn/8);
  int g = rest % GRP;
  int b = rest / GRP;
  int h = tile*8 + row;
  int m = rev5(li);
  float2* lrow = lbuf + row*RPITCH;

  size_t gbase0 = ((size_t)b*Cn + g*CPG)*NPIX + (size_t)h*Wn;
  __half2 hb[12];
#pragma unroll
  for (int k = 0; k < 12; ++k) hb[k] = tmp[gbase0 + 32*k + li];

  float2 acc[12];
#pragma unroll
  for (int k = 0; k < 12; ++k) acc[k] = make_float2(0.f, 0.f);

  for (int j = 0; j < CPG; ++j) {
    size_t gb = gbase0 + (size_t)j*NPIX;
    float2 vc[12];
#pragma unroll
    for (int k = 0; k < 12; ++k) vc[k] = __half22float2(hb[k]);
    if (j + 1 < CPG) {
      size_t gbn = gb + NPIX;
#pragma unroll
      for (int k = 0; k < 12; ++k) hb[k] = tmp[gbn + 32*k + li];
    }
    fft384<1>(vc, li);
    wave_fence();
#pragma unroll
    for (int k = 0; k < 12; ++k) lrow[13*m + k] = vc[k];
    wave_fence();
#pragma unroll
    for (int k = 0; k < 12; ++k) {
      int w = 32*k + li;
      float2 u = lrow[offmap(w)];
      float sr = Sre[gb + w], si = Sim[gb + w];
      acc[k].x += sr*u.x + si*u.y;
      acc[k].y += sr*u.y - si*u.x;
    }
  }
  size_t pbase = ((size_t)g*Bn + b)*NPIX + (size_t)h*Wn;
#pragma unroll
  for (int k = 0; k < 12; ++k) partial[pbase + 32*k + li] = acc[k];
}

// smaps -> packed fp16
__global__ __launch_bounds__(TPB) void k_spack(
    const float* __restrict__ sre, const float* __restrict__ sim,
    __half2* __restrict__ sh)
{
  size_t i = (size_t)blockIdx.x*TPB + threadIdx.x;
  if (i < (size_t)Bn*Cn*NPIX) sh[i] = __floats2half2_rn(sre[i], sim[i]);
}

// lane- and w-scramble-permuted scaled mask + scal zeroing.
// maskP[((b*Wn+wa)*32+li)*12+k] = mask[b][k+12*rev5(li)][wtrue(wa)]/NPIX
// wa = 32*q+s  ->  wtrue = q + 12*rev5(s)
__global__ __launch_bounds__(TPB) void k_maskp(
    const float* __restrict__ mask, float* __restrict__ maskP,
    float* __restrict__ scal)
{
  int idx = blockIdx.x*TPB + threadIdx.x;
  if (blockIdx.x == 0) scal[threadIdx.x] = 0.0f;
  if (idx >= Bn*NPIX) return;
  int k = idx % 12; int t = idx / 12;
  int li = t & 31; t >>= 5;
  int wa = t % Wn; int b = t / Wn;
  int wt = (wa >> 5) + 12*rev5(wa & 31);
  maskP[idx] = mask[((size_t)b*Hn + (k + 12*rev5(li)))*Wn + wt] * (1.0f/(float)NPIX);
}

// column pass: DIF fwd along h -> mask -> DIT inv, all in registers.
// R3: 256 threads, 2 columns per thread (slot, slot+8). LDS 16x415 half2 =
// 25.9KB -> 6 blocks/CU -> entire 1536-block grid co-resident (no tail).
__global__ __launch_bounds__(CTPB, 6) void k_col_full(
    __half2* __restrict__ tmp, const float* __restrict__ maskP)
{
  __shared__ __half2 dbuf[NCOL*CPITCH];
  int tid = threadIdx.x;
  int wave = tid>>6, lane = tid&63, sub = lane>>5, li = lane&31;
  int slot = wave*2 + sub;                 // 0..7
  int tile = blockIdx.x % (Wn/NCOL);
  int bc   = blockIdx.x / (Wn/NCOL);
  int b = bc / Cn;
  int w0 = tile*NCOL;
  size_t tbase = (size_t)bc*NPIX;

  for (int e = tid; e < NCOL*Hn; e += CTPB) {
    int wi = e & (NCOL-1), h = e >> 4;
    dbuf[wi*CPITCH + offmap(h)] = tmp[tbase + (size_t)h*Wn + w0 + wi];
  }
  __syncthreads();

  __half2* drow0 = dbuf + slot*CPITCH;
  __half2* drow1 = dbuf + (slot+8)*CPITCH;
  int wa = w0 + slot, wb = w0 + slot + 8;
  const float4* mp4a = (const float4*)(maskP + (((size_t)b*Wn + wa)*32 + li)*12);
  const float4* mp4b = (const float4*)(maskP + (((size_t)b*Wn + wb)*32 + li)*12);

  float2 v0[12], v1[12];
#pragma unroll
  for (int k = 0; k < 12; ++k) v0[k] = __half22float2(drow0[offmap(32*k + li)]);
#pragma unroll
  for (int k = 0; k < 12; ++k) v1[k] = __half22float2(drow1[offmap(32*k + li)]);

  // issue mask loads early so latency hides under the forward FFTs
  float4 a0 = mp4a[0], a1 = mp4a[1], a2 = mp4a[2];
  fft384<-1>(v0, li);
  float4 b0 = mp4b[0], b1 = mp4b[1], b2 = mp4b[2];
  fft384<-1>(v1, li);

  {
    float mk[12] = {a0.x,a0.y,a0.z,a0.w, a1.x,a1.y,a1.z,a1.w, a2.x,a2.y,a2.z,a2.w};
#pragma unroll
    for (int k = 0; k < 12; ++k) v0[k] = make_float2(v0[k].x*mk[k], v0[k].y*mk[k]);
  }
  fft384_scr<1>(v0, li);
#pragma unroll
  for (int k = 0; k < 12; ++k) drow0[offmap(32*k + li)] = __float22half2_rn(v0[k]);

  {
    float mk[12] = {b0.x,b0.y,b0.z,b0.w, b1.x,b1.y,b1.z,b1.w, b2.x,b2.y,b2.z,b2.w};
#pragma unroll
    for (int k = 0; k < 12; ++k) v1[k] = make_float2(v1[k].x*mk[k], v1[k].y*mk[k]);
  }
  fft384_scr<1>(v1, li);
#pragma unroll
  for (int k = 0; k < 12; ++k) drow1[offmap(32*k + li)] = __float22half2_rn(v1[k]);
  __syncthreads();

  for (int e = tid; e < NCOL*Hn; e += CTPB) {
    int wi = e & (NCOL-1), h = e >> 4;
    tmp[tbase + (size_t)h*Wn + w0 + wi] = dbuf[wi*CPITCH + offmap(h)];
  }
}

// rhs column pass: stage y*mask*(1/384), inverse column FFT; natural tmp out.
__global__ __launch_bounds__(RTPB) void k_col_rhs(
    const float* __restrict__ yre, const float* __restrict__ yim,
    const float* __restrict__ mask, __half2* __restrict__ tmp)
{
  __shared__ float2 dbuf[NCOL*CPITCH_R];
  int tid = threadIdx.x;
  int wave = tid>>6, lane = tid&63, sub = lane>>5, li = lane&31;
  int col = wave*2 + sub;
  int tile = blockIdx.x % (Wn/NCOL);
  int bc   = blockIdx.x / (Wn/NCOL);
  int b = bc / Cn;
  int w0 = tile*NCOL;
  size_t tbase = (size_t)bc*NPIX;
  size_t mbase = (size_t)b*NPIX;

  for (int e = tid; e < NCOL*Hn; e += RTPB) {
    int wi = e & (NCOL-1), h = e >> 4;
    size_t gi = (size_t)h*Wn + w0 + wi;
    float mv = mask[mbase + gi] * (1.0f/384.0f);
    dbuf[wi*CPITCH_R + offmap(h)] = make_float2(yre[tbase+gi]*mv, yim[tbase+gi]*mv);
  }
  __syncthreads();

  float2* drow = dbuf + col*CPITCH_R;
  int m = rev5(li);
  float2 v[12];
#pragma unroll
  for (int k = 0; k < 12; ++k) v[k] = drow[offmap(32*k + li)];
  fft384<1>(v, li);
  wave_fence();
#pragma unroll
  for (int k = 0; k < 12; ++k) drow[13*m + k] = v[k];
  __syncthreads();

  for (int e = tid; e < NCOL*Hn; e += RTPB) {
    int wi = e & (NCOL-1), h = e >> 4;
    tmp[tbase + (size_t)h*Wn + w0 + wi] = __float22half2_rn(dbuf[wi*CPITCH_R + offmap(h)]);
  }
}

// ---------------- CG tail (float4 = 2 complex) ----------------

__device__ __forceinline__ void block_reduce_atomic(float sum, float* target)
{
  __shared__ float red[TPB];
  red[threadIdx.x] = sum; __syncthreads();
  for (int s = TPB/2; s > 0; s >>= 1) {
    if (threadIdx.x < s) red[threadIdx.x] += red[threadIdx.x + s];
    __syncthreads();
  }
  if (threadIdx.x == 0) unsafeAtomicAdd(target, red[0]);
  __syncthreads();
}

__global__ __launch_bounds__(TPB) void k_rhs_init(
    const float* __restrict__ xre, const float* __restrict__ xim,
    const float* __restrict__ lam, const float2* __restrict__ partial,
    float2* __restrict__ r, float2* __restrict__ p, float2* __restrict__ x,
    float* __restrict__ scal)
{
  int b = blockIdx.y;
  float l = lam[0];
  float sum = 0.0f;
  const float2* xr2 = (const float2*)(xre + (size_t)b*NPIX);
  const float2* xi2 = (const float2*)(xim + (size_t)b*NPIX);
  float4* r4 = (float4*)(r + (size_t)b*NPIX);
  float4* p4 = (float4*)(p + (size_t)b*NPIX);
  float4* x4 = (float4*)(x + (size_t)b*NPIX);
  for (int i = blockIdx.x*TPB + threadIdx.x; i < NPIX2; i += RED_BLKS*TPB) {
    float2 re = xr2[i], im = xi2[i];
    float4 rv = make_float4(l*re.x, l*im.x, l*re.y, l*im.y);
#pragma unroll
    for (int g = 0; g < GRP; ++g) {
      float4 pv = ((const float4*)(partial + ((size_t)g*Bn + b)*NPIX))[i];
      rv.x += pv.x; rv.y += pv.y; rv.z += pv.z; rv.w += pv.w;
    }
    r4[i] = rv; p4[i] = rv;
    x4[i] = make_float4(0.f, 0.f, 0.f, 0.f);
    sum += rv.x*rv.x + rv.y*rv.y + rv.z*rv.z + rv.w*rv.w;
  }
  block_reduce_atomic(sum, &scal[b]);
}

// Ap = lambda*p + sum_g partial[g]; dots pAp/ApAp/rAp -> slot[{0,4,8}+b]
__global__ __launch_bounds__(TPB) void k_combine_dot3(
    const float2* __restrict__ p, const float2* __restrict__ r,
    const float* __restrict__ lam, const float2* __restrict__ partial,
    float2* __restrict__ Ap, float* __restrict__ slot)
{
  int b = blockIdx.y;
  float l = lam[0];
  float s_pAp = 0.f, s_AA = 0.f, s_rA = 0.f;
  const float4* p4 = (const float4*)(p + (size_t)b*NPIX);
  const float4* r4 = (const float4*)(r + (size_t)b*NPIX);
  float4* A4 = (float4*)(Ap + (size_t)b*NPIX);
  for (int i = blockIdx.x*TPB + threadIdx.x; i < NPIX2; i += RED_BLKS*TPB) {
    float4 pv = p4[i];
    float4 av = make_float4(l*pv.x, l*pv.y, l*pv.z, l*pv.w);
#pragma unroll
    for (int g = 0; g < GRP; ++g) {
      float4 qv = ((const float4*)(partial + ((size_t)g*Bn + b)*NPIX))[i];
      av.x += qv.x; av.y += qv.y; av.z += qv.z; av.w += qv.w;
    }
    A4[i] = av;
    float4 rv = r4[i];
    s_pAp += pv.x*av.x + pv.y*av.y + pv.z*av.z + pv.w*av.w;
    s_AA  += av.x*av.x + av.y*av.y + av.z*av.z + av.w*av.w;
    s_rA  += rv.x*av.x + rv.y*av.y + rv.z*av.z + rv.w*av.w;
  }
  block_reduce_atomic(s_pAp, &slot[b]);
  block_reduce_atomic(s_AA,  &slot[4+b]);
  block_reduce_atomic(s_rA,  &slot[8+b]);
}

// k_scal folded in: every block recomputes alpha/beta from the reduced slots
// (4 uniform loads); block x==0 persists rTr_{it+1}.
__global__ __launch_bounds__(TPB) void k_upd(
    float2* __restrict__ x, float2* __restrict__ r, float2* __restrict__ p,
    const float2* __restrict__ Ap, float* __restrict__ scal, int it)
{
  int b = blockIdx.y;
  float rtr = scal[it*4 + b];
  const float* slot = scal + 64 + it*12;
  bool act = rtr > TOLF;
  float alpha = act ? rtr / slot[b] : 0.f;
  float rtrn = act ? fmaxf(rtr - 2.f*alpha*slot[8+b] + alpha*alpha*slot[4+b], 0.f) : rtr;
  float beta = act ? rtrn / rtr : 0.f;
  if (blockIdx.x == 0 && threadIdx.x == 0) scal[(it+1)*4 + b] = rtrn;
  if (!act) return;
  float4* x4 = (float4*)(x + (size_t)b*NPIX);
  float4* r4 = (float4*)(r + (size_t)b*NPIX);
  float4* p4 = (float4*)(p + (size_t)b*NPIX);
  const float4* A4 = (const float4*)(Ap + (size_t)b*NPIX);
  for (int i = blockIdx.x*TPB + threadIdx.x; i < NPIX2; i += RED_BLKS*TPB) {
    float4 pv = p4[i], av = A4[i], xv = x4[i], rv = r4[i];
    xv.x += alpha*pv.x; xv.y += alpha*pv.y; xv.z += alpha*pv.z; xv.w += alpha*pv.w;
    rv.x -= alpha*av.x; rv.y -= alpha*av.y; rv.z -= alpha*av.z; rv.w -= alpha*av.w;
    x4[i] = xv; r4[i] = rv;
    p4[i] = make_float4(rv.x + beta*pv.x, rv.y + beta*pv.y,
                        rv.z + beta*pv.z, rv.w + beta*pv.w);
  }
}

// ---------------- launch ----------------

extern "C" void kernel_launch(void* const* d_in, const int* in_sizes, int n_in,
                              void* d_out, int out_size, void* d_ws, size_t ws_size,
                              hipStream_t stream)
{
  const float* lam  = (const float*)d_in[0];
  const float* xre  = (const float*)d_in[1];
  const float* xim  = (const float*)d_in[2];
  const float* yre  = (const float*)d_in[3];
  const float* yim  = (const float*)d_in[4];
  const float* sre  = (const float*)d_in[5];
  const float* sim  = (const float*)d_in[6];
  const float* mask = (const float*)d_in[7];

  const size_t szTmp  = (size_t)Bn*Cn*NPIX*sizeof(__half2);   // 37.7 MB
  const size_t szVec  = (size_t)Bn*NPIX*sizeof(float2);       // 4.7 MB
  const size_t szMask = (size_t)Bn*NPIX*sizeof(float);        // 2.4 MB
  const size_t szSh   = (size_t)Bn*Cn*NPIX*sizeof(__half2);   // 37.7 MB
  const size_t base   = szTmp + (size_t)GRP*szVec + 3*szVec + 2048 + szMask;
  const bool useSh    = (ws_size >= base + szSh);  // ws_size fixed -> stable path

  char* ws = (char*)d_ws;
  __half2* tmp = (__half2*)ws;  ws += szTmp;
  float2* part = (float2*)ws;   ws += (size_t)GRP*szVec;
  float2* r    = (float2*)ws;   ws += szVec;
  float2* p    = (float2*)ws;   ws += szVec;
  float2* Ap   = (float2*)ws;   ws += szVec;
  float*  scal = (float*)ws;    ws += 2048;
  float*  mskP = (float*)ws;    ws += szMask;
  __half2* Sh  = (__half2*)ws;
  float2* x    = (float2*)d_out;

  dim3 blk(TPB);
  dim3 rg(RED_BLKS, Bn);
  int grid_row = Bn*Cn*(Hn/8);       // 3072
  int grid_col = Bn*Cn*(Wn/NCOL);    // 1536
  int grid_inv = Bn*GRP*(Hn/8);      // 768

  k_maskp<<<(Bn*NPIX)/TPB, blk, 0, stream>>>(mask, mskP, scal);
  if (useSh)
    k_spack<<<(Bn*Cn*NPIX)/TPB, blk, 0, stream>>>(sre, sim, Sh);

  // ---- rhs = AH(y) + lambda*x ----
  k_col_rhs<<<grid_col, RTPB, 0, stream>>>(yre, yim, mask, tmp);
  k_row_inv_nat<<<grid_inv, blk, 0, stream>>>(tmp, sre, sim, part);
  k_rhs_init<<<rg, blk, 0, stream>>>(xre, xim, lam, part, r, p, x, scal);

  for (int it = 0; it < NITER; ++it) {
    if (useSh) {
      k_row_fwd<true><<<grid_row, blk, 0, stream>>>(p, sre, sim, Sh, tmp);
      k_col_full<<<grid_col, CTPB, 0, stream>>>(tmp, mskP);
      k_row_inv_scr<true><<<grid_inv, blk, 0, stream>>>(tmp, sre, sim, Sh, part);
    } else {
      k_row_fwd<false><<<grid_row, blk, 0, stream>>>(p, sre, sim, Sh, tmp);
      k_col_full<<<grid_col, CTPB, 0, stream>>>(tmp, mskP);
      k_row_inv_scr<false><<<grid_inv, blk, 0, stream>>>(tmp, sre, sim, Sh, part);
    }
    k_combine_dot3<<<rg, blk, 0, stream>>>(p, r, lam, part, Ap, scal + 64 + it*12);
    k_upd<<<rg, blk, 0, stream>>>(x, r, p, Ap, scal, it);
  }
}

// Round 5
// 1683.280 us; speedup vs baseline: 1.4271x; 1.4271x over previous
//
#include <hip/hip_runtime.h>
#include <hip/hip_fp16.h>

// CG-SENSE: B=4, C=16, H=W=384. x lives in d_out (float2 == [.,2]).
// FFT-384 four-step, wave-synchronous. Forward (DIF): fft12 -> twiddle ->
// fft32 across lanes; output reg k = X[k + 12*rev5(li)] (scrambled).
// Inverse (DIT, fft384_scr): consumes that scrambled register layout directly.
// R1 (measured 1393us): DPP lane exchanges xor1/2/4/8; xor16 via ds_swizzle;
//   select-style butterflies; serial twiddle chain; k_scal folded into k_upd.
// R2/R3 experiments (branchless butterflies, twiddle addition chain,
//   2-col col_full with forced launch bounds) REGRESSED -> all reverted.
//   R3 lesson: launch_bounds min-waves beyond VGPR need => scratch spills
//   (hbm_bytes 7.7e7 -> 5.1e8). Never force occupancy past register budget.
// R4: RED_BLKS 72->288 (CG tail kernels were 4.5 waves/CU; now ~18, and
//   288*256 == NPIX2 so each thread does exactly one float4);
//   k_col_rhs LDS float2->half2 (53.7KB->26.7KB, 2->4 blocks/CU; same
//   medicine that fixed k_col_full in R0).
// tmp fp16 (__half2/complex); smaps packed to fp16 when ws_size allows.

#define Bn 4
#define Cn 16
#define Hn 384
#define Wn 384
#define NPIX (Hn*Wn)
#define NPIX2 (NPIX/2)
#define TPB 256
#define CTPB 512
#define NCOL 16
#define TOLF 1e-10f
#define NITER 10
#define RED_BLKS 288      // 288*256 == NPIX2: one element per thread
#define GRP 4
#define CPG 4
#define RPITCH 416
#define CPITCH 417   // stride mod 32 == 1 (half2 words) -> conflict-light

__device__ __forceinline__ float2 cadd(float2 a, float2 b){ return make_float2(a.x+b.x, a.y+b.y); }
__device__ __forceinline__ float2 csub(float2 a, float2 b){ return make_float2(a.x-b.x, a.y-b.y); }
__device__ __forceinline__ float2 cmulf(float2 a, float2 b){
  return make_float2(a.x*b.x - a.y*b.y, a.x*b.y + a.y*b.x);
}

__device__ __forceinline__ void wave_fence(){ asm volatile("s_waitcnt lgkmcnt(0)" ::: "memory"); }

template<int IMM>
__device__ __forceinline__ float2 shx(float2 v){
  int x = __builtin_amdgcn_ds_swizzle(__float_as_int(v.x), IMM);
  int y = __builtin_amdgcn_ds_swizzle(__float_as_int(v.y), IMM);
  return make_float2(__int_as_float(x), __int_as_float(y));
}

// DPP lane exchange on the VALU pipe (no DS). CTRL: quad_perm/row_ror/mirror.
template<int CTRL>
__device__ __forceinline__ float2 dpp2(float2 v){
  int x = __builtin_amdgcn_mov_dpp(__float_as_int(v.x), CTRL, 0xF, 0xF, true);
  int y = __builtin_amdgcn_mov_dpp(__float_as_int(v.y), CTRL, 0xF, 0xF, true);
  return make_float2(__int_as_float(x), __int_as_float(y));
}
// o[l] = v[l ^ N] within the 32-lane subgroup:
__device__ __forceinline__ float2 xchg1 (float2 v){ return dpp2<0xB1>(v);  }            // quad_perm[1,0,3,2]
__device__ __forceinline__ float2 xchg2 (float2 v){ return dpp2<0x4E>(v);  }            // quad_perm[2,3,0,1]
__device__ __forceinline__ float2 xchg4 (float2 v){ return dpp2<0x1B>(dpp2<0x141>(v)); }// xor7 then xor3
__device__ __forceinline__ float2 xchg8 (float2 v){ return dpp2<0x128>(v); }            // row_ror:8
__device__ __forceinline__ float2 xchg16(float2 v){ return shx<0x401F>(v); }            // crosses DPP row: DS

__device__ __forceinline__ int rev5(int x){
  return ((x&1)<<4) | ((x&2)<<2) | (x&4) | ((x&8)>>2) | ((x&16)>>4);
}

__device__ __forceinline__ int offmap(int w){ return w + ((w*683)>>13); }  // w + w/12, w<384

// ---- in-register FFT-12 (natural in, natural out), kernel w12^(DIR*j*k) ----
template<int DIR>
__device__ __forceinline__ void fft12(float2* v)
{
  const float S3 = (DIR<0) ? -0.86602540378443864676f : 0.86602540378443864676f;
  const float sg = (DIR<0) ? -1.f : 1.f;
  float2 t[4][3];
#pragma unroll
  for (int b = 0; b < 4; ++b) {
    float2 a0 = v[b], a1 = v[4+b], a2 = v[8+b];
    float2 s = cadd(a1,a2), d = csub(a1,a2);
    float2 mm = make_float2(a0.x - 0.5f*s.x, a0.y - 0.5f*s.y);
    float2 e  = make_float2(-d.y*S3, d.x*S3);
    t[b][0] = cadd(a0,s);
    t[b][1] = cadd(mm,e);
    t[b][2] = csub(mm,e);
  }
  const float2 w1  = make_float2(0.86602540378443864676f, sg*0.5f);
  const float2 w2  = make_float2(0.5f, sg*0.86602540378443864676f);
  const float2 w3  = make_float2(0.f, sg);
  const float2 w4t = make_float2(-0.5f, sg*0.86602540378443864676f);
  const float2 w6  = make_float2(-1.f, 0.f);
  t[1][1] = cmulf(t[1][1], w1);  t[1][2] = cmulf(t[1][2], w2);
  t[2][1] = cmulf(t[2][1], w2);  t[2][2] = cmulf(t[2][2], w4t);
  t[3][1] = cmulf(t[3][1], w3);  t[3][2] = cmulf(t[3][2], w6);
#pragma unroll
  for (int c = 0; c < 3; ++c) {
    float2 e = cadd(t[0][c], t[2][c]);
    float2 f = csub(t[0][c], t[2][c]);
    float2 g = cadd(t[1][c], t[3][c]);
    float2 h = csub(t[1][c], t[3][c]);
    float2 ih = (DIR<0) ? make_float2(h.y, -h.x) : make_float2(-h.y, h.x);
    v[c]   = cadd(e,g);
    v[c+3] = cadd(f,ih);
    v[c+6] = csub(e,g);
    v[c+9] = csub(f,ih);
  }
}

// ---- DIF FFT-32 across lanes: natural lane in, bit-reversed lane out ----
template<int DIR>
__device__ __forceinline__ void fft32_lanes(float2* v, int li)
{
  const float c2pi = (DIR<0) ? -6.2831853071795864769f : 6.2831853071795864769f;
  const float sg   = (DIR<0) ? -1.f : 1.f;
  float s, c;
  __sincosf(c2pi*(1.f/32.f)*(float)(li&15), &s, &c); float2 wA = make_float2(c,s);
  __sincosf(c2pi*(1.f/16.f)*(float)(li&7),  &s, &c); float2 wB = make_float2(c,s);
  __sincosf(c2pi*(1.f/ 8.f)*(float)(li&3),  &s, &c); float2 wC = make_float2(c,s);
  bool bA = li & 16, bB = li & 8, bC = li & 4, bD = li & 2, bE = li & 1;
#pragma unroll
  for (int k = 0; k < 12; ++k) {
    float2 a = v[k], o;
    o = xchg16(a); a = bA ? cmulf(csub(o,a), wA) : cadd(a,o);
    o = xchg8 (a); a = bB ? cmulf(csub(o,a), wB) : cadd(a,o);
    o = xchg4 (a); a = bC ? cmulf(csub(o,a), wC) : cadd(a,o);
    o = xchg2 (a);
    { float2 su = cadd(a,o), d = csub(o,a);
      float2 dw = bE ? make_float2(-sg*d.y, sg*d.x) : d;
      a = bD ? dw : su; }
    o = xchg1 (a); a = bE ? csub(o,a) : cadd(a,o);
    v[k] = a;
  }
}

// ---- DIT FFT-32 across lanes: bit-reversed lane in, natural lane out ----
// Transposed network of fft32_lanes: stages reversed, pre-twiddle on hi lanes.
template<int DIR>
__device__ __forceinline__ void fft32_lanes_dit(float2* v, int li)
{
  const float c2pi = (DIR<0) ? -6.2831853071795864769f : 6.2831853071795864769f;
  const float sg   = (DIR<0) ? -1.f : 1.f;
  float s, c;
  __sincosf(c2pi*(1.f/32.f)*(float)(li&15), &s, &c); float2 wA = make_float2(c,s);
  __sincosf(c2pi*(1.f/16.f)*(float)(li&7),  &s, &c); float2 wB = make_float2(c,s);
  __sincosf(c2pi*(1.f/ 8.f)*(float)(li&3),  &s, &c); float2 wC = make_float2(c,s);
  bool bA = li & 16, bB = li & 8, bC = li & 4, bD = li & 2, bE = li & 1;
#pragma unroll
  for (int k = 0; k < 12; ++k) {
    float2 a = v[k], o;
    // E' (xor1), no twiddle
    o = xchg1(a); a = bE ? csub(o,a) : cadd(a,o);
    // D' (xor2), pre-twiddle w4^(li&1) on hi lanes
    { float2 aw = make_float2(-sg*a.y, sg*a.x);      // i*a (sg=+1)
      a = (bD && bE) ? aw : a;
      o = xchg2(a); a = bD ? csub(o,a) : cadd(a,o); }
    // C' (xor4)
    { float2 aw = cmulf(a, wC); a = bC ? aw : a;
      o = xchg4(a); a = bC ? csub(o,a) : cadd(a,o); }
    // B' (xor8)
    { float2 aw = cmulf(a, wB); a = bB ? aw : a;
      o = xchg8(a); a = bB ? csub(o,a) : cadd(a,o); }
    // A' (xor16)
    { float2 aw = cmulf(a, wA); a = bA ? aw : a;
      o = xchg16(a); a = bA ? csub(o,a) : cadd(a,o); }
    v[k] = a;
  }
}

// Forward: in reg k = x[32k+li]. Out reg k1 = X[k1 + 12*rev5(li)].
template<int DIR>
__device__ __forceinline__ void fft384(float2* v, int li)
{
  fft12<DIR>(v);
  const float c2pi = (DIR<0) ? -6.2831853071795864769f : 6.2831853071795864769f;
  float s, c;
  __sincosf(c2pi*(1.f/384.f)*(float)li, &s, &c);
  float2 W = make_float2(c,s), cw = W;
#pragma unroll
  for (int k = 1; k < 12; ++k) { v[k] = cmulf(v[k], cw); cw = cmulf(cw, W); }
  fft32_lanes<DIR>(v, li);
}

// Scrambled-input transform: in reg k = X[k + 12*rev5(li)]. Out reg k = x[32k+li].
template<int DIR>
__device__ __forceinline__ void fft384_scr(float2* v, int li)
{
  fft32_lanes_dit<DIR>(v, li);
  const float c2pi = (DIR<0) ? -6.2831853071795864769f : 6.2831853071795864769f;
  float s, c;
  __sincosf(c2pi*(1.f/384.f)*(float)li, &s, &c);
  float2 W = make_float2(c,s), cw = W;
#pragma unroll
  for (int k = 1; k < 12; ++k) { v[k] = cmulf(v[k], cw); cw = cmulf(cw, W); }
  fft12<DIR>(v);
}

// ---------------- FFT kernels ----------------

// tmp[b,c,h,wa] = scrambled-w FFT_w(S*p). NO LDS (except xor16 swizzles).
template<bool HS>
__global__ __launch_bounds__(TPB) void k_row_fwd(
    const float2* __restrict__ p, const float* __restrict__ Sre,
    const float* __restrict__ Sim, const __half2* __restrict__ Sh,
    __half2* __restrict__ tmp)
{
  int tid = threadIdx.x;
  int wave = tid>>6, lane = tid&63, sub = lane>>5, li = lane&31;
  int row = wave*2 + sub;
  int tile = blockIdx.x % (Hn/8);
  int bc   = blockIdx.x / (Hn/8);
  int b = bc / Cn;
  int h = tile*8 + row;
  size_t gbase = (size_t)bc*NPIX + (size_t)h*Wn;
  size_t pbase = (size_t)b*NPIX + (size_t)h*Wn;

  float2 v[12];
#pragma unroll
  for (int k = 0; k < 12; ++k) {
    int w = 32*k + li;
    float2 pv = p[pbase + w];
    float sr, si;
    if (HS) { float2 sv = __half22float2(Sh[gbase + w]); sr = sv.x; si = sv.y; }
    else    { sr = Sre[gbase + w]; si = Sim[gbase + w]; }
    v[k] = make_float2(sr*pv.x - si*pv.y, sr*pv.y + si*pv.x);
  }
  fft384<-1>(v, li);
#pragma unroll
  for (int k = 0; k < 12; ++k)
    tmp[gbase + 32*k + li] = __float22half2_rn(v[k]);
}

// Iteration path: scrambled tmp -> DIT inverse -> conj(S) acc.
template<bool HS>
__global__ __launch_bounds__(TPB) void k_row_inv_scr(
    const __half2* __restrict__ tmp, const float* __restrict__ Sre,
    const float* __restrict__ Sim, const __half2* __restrict__ Sh,
    float2* __restrict__ partial)
{
  int tid = threadIdx.x;
  int wave = tid>>6, lane = tid&63, sub = lane>>5, li = lane&31;
  int row = wave*2 + sub;
  int tile = blockIdx.x % (Hn/8);
  int rest = blockIdx.x / (Hn/8);
  int g = rest % GRP;
  int b = rest / GRP;
  int h = tile*8 + row;

  size_t gbase0 = ((size_t)b*Cn + g*CPG)*NPIX + (size_t)h*Wn;
  __half2 hb[12];
#pragma unroll
  for (int k = 0; k < 12; ++k) hb[k] = tmp[gbase0 + 32*k + li];

  float2 acc[12];
#pragma unroll
  for (int k = 0; k < 12; ++k) acc[k] = make_float2(0.f, 0.f);

  for (int j = 0; j < CPG; ++j) {
    size_t gb = gbase0 + (size_t)j*NPIX;
    float2 vc[12];
#pragma unroll
    for (int k = 0; k < 12; ++k) vc[k] = __half22float2(hb[k]);
    if (j + 1 < CPG) {
      size_t gbn = gb + NPIX;
#pragma unroll
      for (int k = 0; k < 12; ++k) hb[k] = tmp[gbn + 32*k + li];
    }
    fft384_scr<1>(vc, li);            // natural-w registers
#pragma unroll
    for (int k = 0; k < 12; ++k) {
      int w = 32*k + li;
      float sr, si;
      if (HS) { float2 sv = __half22float2(Sh[gb + w]); sr = sv.x; si = sv.y; }
      else    { sr = Sre[gb + w]; si = Sim[gb + w]; }
      acc[k].x += sr*vc[k].x + si*vc[k].y;
      acc[k].y += sr*vc[k].y - si*vc[k].x;
    }
  }
  size_t pbase = ((size_t)g*Bn + b)*NPIX + (size_t)h*Wn;
#pragma unroll
  for (int k = 0; k < 12; ++k) partial[pbase + 32*k + li] = acc[k];
}

// rhs path (natural tmp from k_col_rhs), runs once: old LDS-unscramble variant.
__global__ __launch_bounds__(TPB) void k_row_inv_nat(
    const __half2* __restrict__ tmp, const float* __restrict__ Sre,
    const float* __restrict__ Sim, float2* __restrict__ partial)
{
  __shared__ float2 lbuf[8*RPITCH];
  int tid = threadIdx.x;
  int wave = tid>>6, lane = tid&63, sub = lane>>5, li = lane&31;
  int row = wave*2 + sub;
  int tile = blockIdx.x % (Hn/8);
  int rest = blockIdx.x / (Hn/8);
  int g = rest % GRP;
  int b = rest / GRP;
  int h = tile*8 + row;
  int m = rev5(li);
  float2* lrow = lbuf + row*RPITCH;

  size_t gbase0 = ((size_t)b*Cn + g*CPG)*NPIX + (size_t)h*Wn;
  __half2 hb[12];
#pragma unroll
  for (int k = 0; k < 12; ++k) hb[k] = tmp[gbase0 + 32*k + li];

  float2 acc[12];
#pragma unroll
  for (int k = 0; k < 12; ++k) acc[k] = make_float2(0.f, 0.f);

  for (int j = 0; j < CPG; ++j) {
    size_t gb = gbase0 + (size_t)j*NPIX;
    float2 vc[12];
#pragma unroll
    for (int k = 0; k < 12; ++k) vc[k] = __half22float2(hb[k]);
    if (j + 1 < CPG) {
      size_t gbn = gb + NPIX;
#pragma unroll
      for (int k = 0; k < 12; ++k) hb[k] = tmp[gbn + 32*k + li];
    }
    fft384<1>(vc, li);
    wave_fence();
#pragma unroll
    for (int k = 0; k < 12; ++k) lrow[13*m + k] = vc[k];
    wave_fence();
#pragma unroll
    for (int k = 0; k < 12; ++k) {
      int w = 32*k + li;
      float2 u = lrow[offmap(w)];
      float sr = Sre[gb + w], si = Sim[gb + w];
      acc[k].x += sr*u.x + si*u.y;
      acc[k].y += sr*u.y - si*u.x;
    }
  }
  size_t pbase = ((size_t)g*Bn + b)*NPIX + (size_t)h*Wn;
#pragma unroll
  for (int k = 0; k < 12; ++k) partial[pbase + 32*k + li] = acc[k];
}

// smaps -> packed fp16
__global__ __launch_bounds__(TPB) void k_spack(
    const float* __restrict__ sre, const float* __restrict__ sim,
    __half2* __restrict__ sh)
{
  size_t i = (size_t)blockIdx.x*TPB + threadIdx.x;
  if (i < (size_t)Bn*Cn*NPIX) sh[i] = __floats2half2_rn(sre[i], sim[i]);
}

// lane- and w-scramble-permuted scaled mask + scal zeroing.
// maskP[((b*Wn+wa)*32+li)*12+k] = mask[b][k+12*rev5(li)][wtrue(wa)]/NPIX
// wa = 32*q+s  ->  wtrue = q + 12*rev5(s)
__global__ __launch_bounds__(TPB) void k_maskp(
    const float* __restrict__ mask, float* __restrict__ maskP,
    float* __restrict__ scal)
{
  int idx = blockIdx.x*TPB + threadIdx.x;
  if (blockIdx.x == 0) scal[threadIdx.x] = 0.0f;
  if (idx >= Bn*NPIX) return;
  int k = idx % 12; int t = idx / 12;
  int li = t & 31; t >>= 5;
  int wa = t % Wn; int b = t / Wn;
  int wt = (wa >> 5) + 12*rev5(wa & 31);
  maskP[idx] = mask[((size_t)b*Hn + (k + 12*rev5(li)))*Wn + wt] * (1.0f/(float)NPIX);
}

// column pass: DIF fwd along h -> mask -> DIT inv, all in registers.
// LDS transpose buffer in __half2 (26.7KB): 4 blocks/CU (wave-capped).
__global__ __launch_bounds__(CTPB) void k_col_full(
    __half2* __restrict__ tmp, const float* __restrict__ maskP)
{
  __shared__ __half2 dbuf[NCOL*CPITCH];
  int tid = threadIdx.x;
  int wave = tid>>6, lane = tid&63, sub = lane>>5, li = lane&31;
  int col = wave*2 + sub;
  int tile = blockIdx.x % (Wn/NCOL);
  int bc   = blockIdx.x / (Wn/NCOL);
  int b = bc / Cn;
  int w0 = tile*NCOL;
  size_t tbase = (size_t)bc*NPIX;

  for (int e = tid; e < NCOL*Hn; e += CTPB) {
    int wi = e & (NCOL-1), h = e >> 4;
    dbuf[wi*CPITCH + offmap(h)] = tmp[tbase + (size_t)h*Wn + w0 + wi];
  }
  __syncthreads();

  __half2* drow = dbuf + col*CPITCH;
  int w = w0 + col;
  const float4* mp4 = (const float4*)(maskP + (((size_t)b*Wn + w)*32 + li)*12);
  float4 m0 = mp4[0], m1 = mp4[1], m2 = mp4[2];
  float2 v[12];
#pragma unroll
  for (int k = 0; k < 12; ++k) v[k] = __half22float2(drow[offmap(32*k + li)]);
  fft384<-1>(v, li);                       // scrambled-h regs
  float mk[12] = {m0.x,m0.y,m0.z,m0.w, m1.x,m1.y,m1.z,m1.w, m2.x,m2.y,m2.z,m2.w};
#pragma unroll
  for (int k = 0; k < 12; ++k) v[k] = make_float2(v[k].x*mk[k], v[k].y*mk[k]);
  fft384_scr<1>(v, li);                    // natural-h regs
#pragma unroll
  for (int k = 0; k < 12; ++k) drow[offmap(32*k + li)] = __float22half2_rn(v[k]);  // own column, in-order DS
  __syncthreads();

  for (int e = tid; e < NCOL*Hn; e += CTPB) {
    int wi = e & (NCOL-1), h = e >> 4;
    tmp[tbase + (size_t)h*Wn + w0 + wi] = dbuf[wi*CPITCH + offmap(h)];
  }
}

// rhs column pass: stage y*mask*(1/384) (fp16), inverse column FFT; natural
// tmp out. R4: dbuf in __half2 -> 26.7KB -> 4 blocks/CU (was 2).
__global__ __launch_bounds__(CTPB) void k_col_rhs(
    const float* __restrict__ yre, const float* __restrict__ yim,
    const float* __restrict__ mask, __half2* __restrict__ tmp)
{
  __shared__ __half2 dbuf[NCOL*CPITCH];
  int tid = threadIdx.x;
  int wave = tid>>6, lane = tid&63, sub = lane>>5, li = lane&31;
  int col = wave*2 + sub;
  int tile = blockIdx.x % (Wn/NCOL);
  int bc   = blockIdx.x / (Wn/NCOL);
  int b = bc / Cn;
  int w0 = tile*NCOL;
  size_t tbase = (size_t)bc*NPIX;
  size_t mbase = (size_t)b*NPIX;

  for (int e = tid; e < NCOL*Hn; e += CTPB) {
    int wi = e & (NCOL-1), h = e >> 4;
    size_t gi = (size_t)h*Wn + w0 + wi;
    float mv = mask[mbase + gi] * (1.0f/384.0f);
    dbuf[wi*CPITCH + offmap(h)] =
        __floats2half2_rn(yre[tbase+gi]*mv, yim[tbase+gi]*mv);
  }
  __syncthreads();

  __half2* drow = dbuf + col*CPITCH;
  int m = rev5(li);
  float2 v[12];
#pragma unroll
  for (int k = 0; k < 12; ++k) v[k] = __half22float2(drow[offmap(32*k + li)]);
  fft384<1>(v, li);
  wave_fence();
#pragma unroll
  for (int k = 0; k < 12; ++k) drow[13*m + k] = __float22half2_rn(v[k]);
  __syncthreads();

  for (int e = tid; e < NCOL*Hn; e += CTPB) {
    int wi = e & (NCOL-1), h = e >> 4;
    tmp[tbase + (size_t)h*Wn + w0 + wi] = dbuf[wi*CPITCH + offmap(h)];
  }
}

// ---------------- CG tail (float4 = 2 complex) ----------------

__device__ __forceinline__ void block_reduce_atomic(float sum, float* target)
{
  __shared__ float red[TPB];
  red[threadIdx.x] = sum; __syncthreads();
  for (int s = TPB/2; s > 0; s >>= 1) {
    if (threadIdx.x < s) red[threadIdx.x] += red[threadIdx.x + s];
    __syncthreads();
  }
  if (threadIdx.x == 0) unsafeAtomicAdd(target, red[0]);
  __syncthreads();
}

__global__ __launch_bounds__(TPB) void k_rhs_init(
    const float* __restrict__ xre, const float* __restrict__ xim,
    const float* __restrict__ lam, const float2* __restrict__ partial,
    float2* __restrict__ r, float2* __restrict__ p, float2* __restrict__ x,
    float* __restrict__ scal)
{
  int b = blockIdx.y;
  float l = lam[0];
  float sum = 0.0f;
  const float2* xr2 = (const float2*)(xre + (size_t)b*NPIX);
  const float2* xi2 = (const float2*)(xim + (size_t)b*NPIX);
  float4* r4 = (float4*)(r + (size_t)b*NPIX);
  float4* p4 = (float4*)(p + (size_t)b*NPIX);
  float4* x4 = (float4*)(x + (size_t)b*NPIX);
  for (int i = blockIdx.x*TPB + threadIdx.x; i < NPIX2; i += RED_BLKS*TPB) {
    float2 re = xr2[i], im = xi2[i];
    float4 rv = make_float4(l*re.x, l*im.x, l*re.y, l*im.y);
#pragma unroll
    for (int g = 0; g < GRP; ++g) {
      float4 pv = ((const float4*)(partial + ((size_t)g*Bn + b)*NPIX))[i];
      rv.x += pv.x; rv.y += pv.y; rv.z += pv.z; rv.w += pv.w;
    }
    r4[i] = rv; p4[i] = rv;
    x4[i] = make_float4(0.f, 0.f, 0.f, 0.f);
    sum += rv.x*rv.x + rv.y*rv.y + rv.z*rv.z + rv.w*rv.w;
  }
  block_reduce_atomic(sum, &scal[b]);
}

// Ap = lambda*p + sum_g partial[g]; dots pAp/ApAp/rAp -> slot[{0,4,8}+b]
__global__ __launch_bounds__(TPB) void k_combine_dot3(
    const float2* __restrict__ p, const float2* __restrict__ r,
    const float* __restrict__ lam, const float2* __restrict__ partial,
    float2* __restrict__ Ap, float* __restrict__ slot)
{
  int b = blockIdx.y;
  float l = lam[0];
  float s_pAp = 0.f, s_AA = 0.f, s_rA = 0.f;
  const float4* p4 = (const float4*)(p + (size_t)b*NPIX);
  const float4* r4 = (const float4*)(r + (size_t)b*NPIX);
  float4* A4 = (float4*)(Ap + (size_t)b*NPIX);
  for (int i = blockIdx.x*TPB + threadIdx.x; i < NPIX2; i += RED_BLKS*TPB) {
    float4 pv = p4[i];
    float4 av = make_float4(l*pv.x, l*pv.y, l*pv.z, l*pv.w);
#pragma unroll
    for (int g = 0; g < GRP; ++g) {
      float4 qv = ((const float4*)(partial + ((size_t)g*Bn + b)*NPIX))[i];
      av.x += qv.x; av.y += qv.y; av.z += qv.z; av.w += qv.w;
    }
    A4[i] = av;
    float4 rv = r4[i];
    s_pAp += pv.x*av.x + pv.y*av.y + pv.z*av.z + pv.w*av.w;
    s_AA  += av.x*av.x + av.y*av.y + av.z*av.z + av.w*av.w;
    s_rA  += rv.x*av.x + rv.y*av.y + rv.z*av.z + rv.w*av.w;
  }
  block_reduce_atomic(s_pAp, &slot[b]);
  block_reduce_atomic(s_AA,  &slot[4+b]);
  block_reduce_atomic(s_rA,  &slot[8+b]);
}

// k_scal folded in: every block recomputes alpha/beta from the reduced slots
// (4 uniform loads); block x==0 persists rTr_{it+1}.
__global__ __launch_bounds__(TPB) void k_upd(
    float2* __restrict__ x, float2* __restrict__ r, float2* __restrict__ p,
    const float2* __restrict__ Ap, float* __restrict__ scal, int it)
{
  int b = blockIdx.y;
  float rtr = scal[it*4 + b];
  const float* slot = scal + 64 + it*12;
  bool act = rtr > TOLF;
  float alpha = act ? rtr / slot[b] : 0.f;
  float rtrn = act ? fmaxf(rtr - 2.f*alpha*slot[8+b] + alpha*alpha*slot[4+b], 0.f) : rtr;
  float beta = act ? rtrn / rtr : 0.f;
  if (blockIdx.x == 0 && threadIdx.x == 0) scal[(it+1)*4 + b] = rtrn;
  if (!act) return;
  float4* x4 = (float4*)(x + (size_t)b*NPIX);
  float4* r4 = (float4*)(r + (size_t)b*NPIX);
  float4* p4 = (float4*)(p + (size_t)b*NPIX);
  const float4* A4 = (const float4*)(Ap + (size_t)b*NPIX);
  for (int i = blockIdx.x*TPB + threadIdx.x; i < NPIX2; i += RED_BLKS*TPB) {
    float4 pv = p4[i], av = A4[i], xv = x4[i], rv = r4[i];
    xv.x += alpha*pv.x; xv.y += alpha*pv.y; xv.z += alpha*pv.z; xv.w += alpha*pv.w;
    rv.x -= alpha*av.x; rv.y -= alpha*av.y; rv.z -= alpha*av.z; rv.w -= alpha*av.w;
    x4[i] = xv; r4[i] = rv;
    p4[i] = make_float4(rv.x + beta*pv.x, rv.y + beta*pv.y,
                        rv.z + beta*pv.z, rv.w + beta*pv.w);
  }
}

// ---------------- launch ----------------

extern "C" void kernel_launch(void* const* d_in, const int* in_sizes, int n_in,
                              void* d_out, int out_size, void* d_ws, size_t ws_size,
                              hipStream_t stream)
{
  const float* lam  = (const float*)d_in[0];
  const float* xre  = (const float*)d_in[1];
  const float* xim  = (const float*)d_in[2];
  const float* yre  = (const float*)d_in[3];
  const float* yim  = (const float*)d_in[4];
  const float* sre  = (const float*)d_in[5];
  const float* sim  = (const float*)d_in[6];
  const float* mask = (const float*)d_in[7];

  const size_t szTmp  = (size_t)Bn*Cn*NPIX*sizeof(__half2);   // 37.7 MB
  const size_t szVec  = (size_t)Bn*NPIX*sizeof(float2);       // 4.7 MB
  const size_t szMask = (size_t)Bn*NPIX*sizeof(float);        // 2.4 MB
  const size_t szSh   = (size_t)Bn*Cn*NPIX*sizeof(__half2);   // 37.7 MB
  const size_t base   = szTmp + (size_t)GRP*szVec + 3*szVec + 2048 + szMask;
  const bool useSh    = (ws_size >= base + szSh);  // ws_size fixed -> stable path

  char* ws = (char*)d_ws;
  __half2* tmp = (__half2*)ws;  ws += szTmp;
  float2* part = (float2*)ws;   ws += (size_t)GRP*szVec;
  float2* r    = (float2*)ws;   ws += szVec;
  float2* p    = (float2*)ws;   ws += szVec;
  float2* Ap   = (float2*)ws;   ws += szVec;
  float*  scal = (float*)ws;    ws += 2048;
  float*  mskP = (float*)ws;    ws += szMask;
  __half2* Sh  = (__half2*)ws;
  float2* x    = (float2*)d_out;

  dim3 blk(TPB);
  dim3 rg(RED_BLKS, Bn);
  int grid_row = Bn*Cn*(Hn/8);       // 3072
  int grid_col = Bn*Cn*(Wn/NCOL);    // 1536
  int grid_inv = Bn*GRP*(Hn/8);      // 768

  k_maskp<<<(Bn*NPIX)/TPB, blk, 0, stream>>>(mask, mskP, scal);
  if (useSh)
    k_spack<<<(Bn*Cn*NPIX)/TPB, blk, 0, stream>>>(sre, sim, Sh);

  // ---- rhs = AH(y) + lambda*x ----
  k_col_rhs<<<grid_col, CTPB, 0, stream>>>(yre, yim, mask, tmp);
  k_row_inv_nat<<<grid_inv, blk, 0, stream>>>(tmp, sre, sim, part);
  k_rhs_init<<<rg, blk, 0, stream>>>(xre, xim, lam, part, r, p, x, scal);

  for (int it = 0; it < NITER; ++it) {
    if (useSh) {
      k_row_fwd<true><<<grid_row, blk, 0, stream>>>(p, sre, sim, Sh, tmp);
      k_col_full<<<grid_col, CTPB, 0, stream>>>(tmp, mskP);
      k_row_inv_scr<true><<<grid_inv, blk, 0, stream>>>(tmp, sre, sim, Sh, part);
    } else {
      k_row_fwd<false><<<grid_row, blk, 0, stream>>>(p, sre, sim, Sh, tmp);
      k_col_full<<<grid_col, CTPB, 0, stream>>>(tmp, mskP);
      k_row_inv_scr<false><<<grid_inv, blk, 0, stream>>>(tmp, sre, sim, Sh, part);
    }
    k_combine_dot3<<<rg, blk, 0, stream>>>(p, r, lam, part, Ap, scal + 64 + it*12);
    k_upd<<<rg, blk, 0, stream>>>(x, r, p, Ap, scal, it);
  }
}

// Round 6
// 1390.886 us; speedup vs baseline: 1.7271x; 1.2102x over previous
//
#include <hip/hip_runtime.h>
#include <hip/hip_fp16.h>

// CG-SENSE: B=4, C=16, H=W=384. x lives in d_out (float2 == [.,2]).
// FFT-384 four-step, wave-synchronous. Forward (DIF): fft12 -> twiddle ->
// fft32 across lanes; output reg k = X[k + 12*rev5(li)] (scrambled).
// Inverse (DIT, fft384_scr): consumes that scrambled register layout directly.
// R1 (measured 1393us, best): DPP lane exchanges xor1/2/4/8; xor16 via
//   ds_swizzle; select-style butterflies; serial twiddle chain; k_scal folded
//   into k_upd; k_col_full LDS in half2 (26.5KB); k_col_rhs LDS float2.
// REFUTED experiments (kept out): branchless butterflies (R2), twiddle
//   addition chain (R2), forced launch_bounds occupancy (R3: scratch spill,
//   hbm_bytes 7.7e7->5.1e8), RED_BLKS=288 (R4: 4x atomic serialization),
//   k_col_rhs half2 staging (R4: +4us, occupancy dropped).
// R5: exact R1 source + ONE isolated change: block_reduce_atomic now
//   wave-shuffle butterfly + 1 LDS slot/wave + single atomic (2 syncs vs 8).
// tmp fp16 (__half2/complex); smaps packed to fp16 when ws_size allows.

#define Bn 4
#define Cn 16
#define Hn 384
#define Wn 384
#define NPIX (Hn*Wn)
#define NPIX2 (NPIX/2)
#define TPB 256
#define CTPB 512
#define NCOL 16
#define TOLF 1e-10f
#define NITER 10
#define RED_BLKS 72
#define GRP 4
#define CPG 4
#define RPITCH 416
#define CPITCH 417   // stride mod 32 == 1 (half2 words) -> conflict-light

__device__ __forceinline__ float2 cadd(float2 a, float2 b){ return make_float2(a.x+b.x, a.y+b.y); }
__device__ __forceinline__ float2 csub(float2 a, float2 b){ return make_float2(a.x-b.x, a.y-b.y); }
__device__ __forceinline__ float2 cmulf(float2 a, float2 b){
  return make_float2(a.x*b.x - a.y*b.y, a.x*b.y + a.y*b.x);
}

__device__ __forceinline__ void wave_fence(){ asm volatile("s_waitcnt lgkmcnt(0)" ::: "memory"); }

template<int IMM>
__device__ __forceinline__ float2 shx(float2 v){
  int x = __builtin_amdgcn_ds_swizzle(__float_as_int(v.x), IMM);
  int y = __builtin_amdgcn_ds_swizzle(__float_as_int(v.y), IMM);
  return make_float2(__int_as_float(x), __int_as_float(y));
}

// DPP lane exchange on the VALU pipe (no DS). CTRL: quad_perm/row_ror/mirror.
template<int CTRL>
__device__ __forceinline__ float2 dpp2(float2 v){
  int x = __builtin_amdgcn_mov_dpp(__float_as_int(v.x), CTRL, 0xF, 0xF, true);
  int y = __builtin_amdgcn_mov_dpp(__float_as_int(v.y), CTRL, 0xF, 0xF, true);
  return make_float2(__int_as_float(x), __int_as_float(y));
}
// o[l] = v[l ^ N] within the 32-lane subgroup:
__device__ __forceinline__ float2 xchg1 (float2 v){ return dpp2<0xB1>(v);  }            // quad_perm[1,0,3,2]
__device__ __forceinline__ float2 xchg2 (float2 v){ return dpp2<0x4E>(v);  }            // quad_perm[2,3,0,1]
__device__ __forceinline__ float2 xchg4 (float2 v){ return dpp2<0x1B>(dpp2<0x141>(v)); }// xor7 then xor3
__device__ __forceinline__ float2 xchg8 (float2 v){ return dpp2<0x128>(v); }            // row_ror:8
__device__ __forceinline__ float2 xchg16(float2 v){ return shx<0x401F>(v); }            // crosses DPP row: DS

__device__ __forceinline__ int rev5(int x){
  return ((x&1)<<4) | ((x&2)<<2) | (x&4) | ((x&8)>>2) | ((x&16)>>4);
}

__device__ __forceinline__ int offmap(int w){ return w + ((w*683)>>13); }  // w + w/12, w<384

// ---- in-register FFT-12 (natural in, natural out), kernel w12^(DIR*j*k) ----
template<int DIR>
__device__ __forceinline__ void fft12(float2* v)
{
  const float S3 = (DIR<0) ? -0.86602540378443864676f : 0.86602540378443864676f;
  const float sg = (DIR<0) ? -1.f : 1.f;
  float2 t[4][3];
#pragma unroll
  for (int b = 0; b < 4; ++b) {
    float2 a0 = v[b], a1 = v[4+b], a2 = v[8+b];
    float2 s = cadd(a1,a2), d = csub(a1,a2);
    float2 mm = make_float2(a0.x - 0.5f*s.x, a0.y - 0.5f*s.y);
    float2 e  = make_float2(-d.y*S3, d.x*S3);
    t[b][0] = cadd(a0,s);
    t[b][1] = cadd(mm,e);
    t[b][2] = csub(mm,e);
  }
  const float2 w1  = make_float2(0.86602540378443864676f, sg*0.5f);
  const float2 w2  = make_float2(0.5f, sg*0.86602540378443864676f);
  const float2 w3  = make_float2(0.f, sg);
  const float2 w4t = make_float2(-0.5f, sg*0.86602540378443864676f);
  const float2 w6  = make_float2(-1.f, 0.f);
  t[1][1] = cmulf(t[1][1], w1);  t[1][2] = cmulf(t[1][2], w2);
  t[2][1] = cmulf(t[2][1], w2);  t[2][2] = cmulf(t[2][2], w4t);
  t[3][1] = cmulf(t[3][1], w3);  t[3][2] = cmulf(t[3][2], w6);
#pragma unroll
  for (int c = 0; c < 3; ++c) {
    float2 e = cadd(t[0][c], t[2][c]);
    float2 f = csub(t[0][c], t[2][c]);
    float2 g = cadd(t[1][c], t[3][c]);
    float2 h = csub(t[1][c], t[3][c]);
    float2 ih = (DIR<0) ? make_float2(h.y, -h.x) : make_float2(-h.y, h.x);
    v[c]   = cadd(e,g);
    v[c+3] = cadd(f,ih);
    v[c+6] = csub(e,g);
    v[c+9] = csub(f,ih);
  }
}

// ---- DIF FFT-32 across lanes: natural lane in, bit-reversed lane out ----
template<int DIR>
__device__ __forceinline__ void fft32_lanes(float2* v, int li)
{
  const float c2pi = (DIR<0) ? -6.2831853071795864769f : 6.2831853071795864769f;
  const float sg   = (DIR<0) ? -1.f : 1.f;
  float s, c;
  __sincosf(c2pi*(1.f/32.f)*(float)(li&15), &s, &c); float2 wA = make_float2(c,s);
  __sincosf(c2pi*(1.f/16.f)*(float)(li&7),  &s, &c); float2 wB = make_float2(c,s);
  __sincosf(c2pi*(1.f/ 8.f)*(float)(li&3),  &s, &c); float2 wC = make_float2(c,s);
  bool bA = li & 16, bB = li & 8, bC = li & 4, bD = li & 2, bE = li & 1;
#pragma unroll
  for (int k = 0; k < 12; ++k) {
    float2 a = v[k], o;
    o = xchg16(a); a = bA ? cmulf(csub(o,a), wA) : cadd(a,o);
    o = xchg8 (a); a = bB ? cmulf(csub(o,a), wB) : cadd(a,o);
    o = xchg4 (a); a = bC ? cmulf(csub(o,a), wC) : cadd(a,o);
    o = xchg2 (a);
    { float2 su = cadd(a,o), d = csub(o,a);
      float2 dw = bE ? make_float2(-sg*d.y, sg*d.x) : d;
      a = bD ? dw : su; }
    o = xchg1 (a); a = bE ? csub(o,a) : cadd(a,o);
    v[k] = a;
  }
}

// ---- DIT FFT-32 across lanes: bit-reversed lane in, natural lane out ----
// Transposed network of fft32_lanes: stages reversed, pre-twiddle on hi lanes.
template<int DIR>
__device__ __forceinline__ void fft32_lanes_dit(float2* v, int li)
{
  const float c2pi = (DIR<0) ? -6.2831853071795864769f : 6.2831853071795864769f;
  const float sg   = (DIR<0) ? -1.f : 1.f;
  float s, c;
  __sincosf(c2pi*(1.f/32.f)*(float)(li&15), &s, &c); float2 wA = make_float2(c,s);
  __sincosf(c2pi*(1.f/16.f)*(float)(li&7),  &s, &c); float2 wB = make_float2(c,s);
  __sincosf(c2pi*(1.f/ 8.f)*(float)(li&3),  &s, &c); float2 wC = make_float2(c,s);
  bool bA = li & 16, bB = li & 8, bC = li & 4, bD = li & 2, bE = li & 1;
#pragma unroll
  for (int k = 0; k < 12; ++k) {
    float2 a = v[k], o;
    // E' (xor1), no twiddle
    o = xchg1(a); a = bE ? csub(o,a) : cadd(a,o);
    // D' (xor2), pre-twiddle w4^(li&1) on hi lanes
    { float2 aw = make_float2(-sg*a.y, sg*a.x);      // i*a (sg=+1)
      a = (bD && bE) ? aw : a;
      o = xchg2(a); a = bD ? csub(o,a) : cadd(a,o); }
    // C' (xor4)
    { float2 aw = cmulf(a, wC); a = bC ? aw : a;
      o = xchg4(a); a = bC ? csub(o,a) : cadd(a,o); }
    // B' (xor8)
    { float2 aw = cmulf(a, wB); a = bB ? aw : a;
      o = xchg8(a); a = bB ? csub(o,a) : cadd(a,o); }
    // A' (xor16)
    { float2 aw = cmulf(a, wA); a = bA ? aw : a;
      o = xchg16(a); a = bA ? csub(o,a) : cadd(a,o); }
    v[k] = a;
  }
}

// Forward: in reg k = x[32k+li]. Out reg k1 = X[k1 + 12*rev5(li)].
template<int DIR>
__device__ __forceinline__ void fft384(float2* v, int li)
{
  fft12<DIR>(v);
  const float c2pi = (DIR<0) ? -6.2831853071795864769f : 6.2831853071795864769f;
  float s, c;
  __sincosf(c2pi*(1.f/384.f)*(float)li, &s, &c);
  float2 W = make_float2(c,s), cw = W;
#pragma unroll
  for (int k = 1; k < 12; ++k) { v[k] = cmulf(v[k], cw); cw = cmulf(cw, W); }
  fft32_lanes<DIR>(v, li);
}

// Scrambled-input transform: in reg k = X[k + 12*rev5(li)]. Out reg k = x[32k+li].
template<int DIR>
__device__ __forceinline__ void fft384_scr(float2* v, int li)
{
  fft32_lanes_dit<DIR>(v, li);
  const float c2pi = (DIR<0) ? -6.2831853071795864769f : 6.2831853071795864769f;
  float s, c;
  __sincosf(c2pi*(1.f/384.f)*(float)li, &s, &c);
  float2 W = make_float2(c,s), cw = W;
#pragma unroll
  for (int k = 1; k < 12; ++k) { v[k] = cmulf(v[k], cw); cw = cmulf(cw, W); }
  fft12<DIR>(v);
}

// ---------------- FFT kernels ----------------

// tmp[b,c,h,wa] = scrambled-w FFT_w(S*p). NO LDS (except xor16 swizzles).
template<bool HS>
__global__ __launch_bounds__(TPB) void k_row_fwd(
    const float2* __restrict__ p, const float* __restrict__ Sre,
    const float* __restrict__ Sim, const __half2* __restrict__ Sh,
    __half2* __restrict__ tmp)
{
  int tid = threadIdx.x;
  int wave = tid>>6, lane = tid&63, sub = lane>>5, li = lane&31;
  int row = wave*2 + sub;
  int tile = blockIdx.x % (Hn/8);
  int bc   = blockIdx.x / (Hn/8);
  int b = bc / Cn;
  int h = tile*8 + row;
  size_t gbase = (size_t)bc*NPIX + (size_t)h*Wn;
  size_t pbase = (size_t)b*NPIX + (size_t)h*Wn;

  float2 v[12];
#pragma unroll
  for (int k = 0; k < 12; ++k) {
    int w = 32*k + li;
    float2 pv = p[pbase + w];
    float sr, si;
    if (HS) { float2 sv = __half22float2(Sh[gbase + w]); sr = sv.x; si = sv.y; }
    else    { sr = Sre[gbase + w]; si = Sim[gbase + w]; }
    v[k] = make_float2(sr*pv.x - si*pv.y, sr*pv.y + si*pv.x);
  }
  fft384<-1>(v, li);
#pragma unroll
  for (int k = 0; k < 12; ++k)
    tmp[gbase + 32*k + li] = __float22half2_rn(v[k]);
}

// Iteration path: scrambled tmp -> DIT inverse -> conj(S) acc.
template<bool HS>
__global__ __launch_bounds__(TPB) void k_row_inv_scr(
    const __half2* __restrict__ tmp, const float* __restrict__ Sre,
    const float* __restrict__ Sim, const __half2* __restrict__ Sh,
    float2* __restrict__ partial)
{
  int tid = threadIdx.x;
  int wave = tid>>6, lane = tid&63, sub = lane>>5, li = lane&31;
  int row = wave*2 + sub;
  int tile = blockIdx.x % (Hn/8);
  int rest = blockIdx.x / (Hn/8);
  int g = rest % GRP;
  int b = rest / GRP;
  int h = tile*8 + row;

  size_t gbase0 = ((size_t)b*Cn + g*CPG)*NPIX + (size_t)h*Wn;
  __half2 hb[12];
#pragma unroll
  for (int k = 0; k < 12; ++k) hb[k] = tmp[gbase0 + 32*k + li];

  float2 acc[12];
#pragma unroll
  for (int k = 0; k < 12; ++k) acc[k] = make_float2(0.f, 0.f);

  for (int j = 0; j < CPG; ++j) {
    size_t gb = gbase0 + (size_t)j*NPIX;
    float2 vc[12];
#pragma unroll
    for (int k = 0; k < 12; ++k) vc[k] = __half22float2(hb[k]);
    if (j + 1 < CPG) {
      size_t gbn = gb + NPIX;
#pragma unroll
      for (int k = 0; k < 12; ++k) hb[k] = tmp[gbn + 32*k + li];
    }
    fft384_scr<1>(vc, li);            // natural-w registers
#pragma unroll
    for (int k = 0; k < 12; ++k) {
      int w = 32*k + li;
      float sr, si;
      if (HS) { float2 sv = __half22float2(Sh[gb + w]); sr = sv.x; si = sv.y; }
      else    { sr = Sre[gb + w]; si = Sim[gb + w]; }
      acc[k].x += sr*vc[k].x + si*vc[k].y;
      acc[k].y += sr*vc[k].y - si*vc[k].x;
    }
  }
  size_t pbase = ((size_t)g*Bn + b)*NPIX + (size_t)h*Wn;
#pragma unroll
  for (int k = 0; k < 12; ++k) partial[pbase + 32*k + li] = acc[k];
}

// rhs path (natural tmp from k_col_rhs), runs once: old LDS-unscramble variant.
__global__ __launch_bounds__(TPB) void k_row_inv_nat(
    const __half2* __restrict__ tmp, const float* __restrict__ Sre,
    const float* __restrict__ Sim, float2* __restrict__ partial)
{
  __shared__ float2 lbuf[8*RPITCH];
  int tid = threadIdx.x;
  int wave = tid>>6, lane = tid&63, sub = lane>>5, li = lane&31;
  int row = wave*2 + sub;
  int tile = blockIdx.x % (Hn/8);
  int rest = blockIdx.x / (Hn/8);
  int g = rest % GRP;
  int b = rest / GRP;
  int h = tile*8 + row;
  int m = rev5(li);
  float2* lrow = lbuf + row*RPITCH;

  size_t gbase0 = ((size_t)b*Cn + g*CPG)*NPIX + (size_t)h*Wn;
  __half2 hb[12];
#pragma unroll
  for (int k = 0; k < 12; ++k) hb[k] = tmp[gbase0 + 32*k + li];

  float2 acc[12];
#pragma unroll
  for (int k = 0; k < 12; ++k) acc[k] = make_float2(0.f, 0.f);

  for (int j = 0; j < CPG; ++j) {
    size_t gb = gbase0 + (size_t)j*NPIX;
    float2 vc[12];
#pragma unroll
    for (int k = 0; k < 12; ++k) vc[k] = __half22float2(hb[k]);
    if (j + 1 < CPG) {
      size_t gbn = gb + NPIX;
#pragma unroll
      for (int k = 0; k < 12; ++k) hb[k] = tmp[gbn + 32*k + li];
    }
    fft384<1>(vc, li);
    wave_fence();
#pragma unroll
    for (int k = 0; k < 12; ++k) lrow[13*m + k] = vc[k];
    wave_fence();
#pragma unroll
    for (int k = 0; k < 12; ++k) {
      int w = 32*k + li;
      float2 u = lrow[offmap(w)];
      float sr = Sre[gb + w], si = Sim[gb + w];
      acc[k].x += sr*u.x + si*u.y;
      acc[k].y += sr*u.y - si*u.x;
    }
  }
  size_t pbase = ((size_t)g*Bn + b)*NPIX + (size_t)h*Wn;
#pragma unroll
  for (int k = 0; k < 12; ++k) partial[pbase + 32*k + li] = acc[k];
}

// smaps -> packed fp16
__global__ __launch_bounds__(TPB) void k_spack(
    const float* __restrict__ sre, const float* __restrict__ sim,
    __half2* __restrict__ sh)
{
  size_t i = (size_t)blockIdx.x*TPB + threadIdx.x;
  if (i < (size_t)Bn*Cn*NPIX) sh[i] = __floats2half2_rn(sre[i], sim[i]);
}

// lane- and w-scramble-permuted scaled mask + scal zeroing.
// maskP[((b*Wn+wa)*32+li)*12+k] = mask[b][k+12*rev5(li)][wtrue(wa)]/NPIX
// wa = 32*q+s  ->  wtrue = q + 12*rev5(s)
__global__ __launch_bounds__(TPB) void k_maskp(
    const float* __restrict__ mask, float* __restrict__ maskP,
    float* __restrict__ scal)
{
  int idx = blockIdx.x*TPB + threadIdx.x;
  if (blockIdx.x == 0) scal[threadIdx.x] = 0.0f;
  if (idx >= Bn*NPIX) return;
  int k = idx % 12; int t = idx / 12;
  int li = t & 31; t >>= 5;
  int wa = t % Wn; int b = t / Wn;
  int wt = (wa >> 5) + 12*rev5(wa & 31);
  maskP[idx] = mask[((size_t)b*Hn + (k + 12*rev5(li)))*Wn + wt] * (1.0f/(float)NPIX);
}

// column pass: DIF fwd along h -> mask -> DIT inv, all in registers.
// LDS transpose buffer in __half2 (26.7KB).
__global__ __launch_bounds__(CTPB) void k_col_full(
    __half2* __restrict__ tmp, const float* __restrict__ maskP)
{
  __shared__ __half2 dbuf[NCOL*CPITCH];
  int tid = threadIdx.x;
  int wave = tid>>6, lane = tid&63, sub = lane>>5, li = lane&31;
  int col = wave*2 + sub;
  int tile = blockIdx.x % (Wn/NCOL);
  int bc   = blockIdx.x / (Wn/NCOL);
  int b = bc / Cn;
  int w0 = tile*NCOL;
  size_t tbase = (size_t)bc*NPIX;

  for (int e = tid; e < NCOL*Hn; e += CTPB) {
    int wi = e & (NCOL-1), h = e >> 4;
    dbuf[wi*CPITCH + offmap(h)] = tmp[tbase + (size_t)h*Wn + w0 + wi];
  }
  __syncthreads();

  __half2* drow = dbuf + col*CPITCH;
  int w = w0 + col;
  const float4* mp4 = (const float4*)(maskP + (((size_t)b*Wn + w)*32 + li)*12);
  float4 m0 = mp4[0], m1 = mp4[1], m2 = mp4[2];
  float2 v[12];
#pragma unroll
  for (int k = 0; k < 12; ++k) v[k] = __half22float2(drow[offmap(32*k + li)]);
  fft384<-1>(v, li);                       // scrambled-h regs
  float mk[12] = {m0.x,m0.y,m0.z,m0.w, m1.x,m1.y,m1.z,m1.w, m2.x,m2.y,m2.z,m2.w};
#pragma unroll
  for (int k = 0; k < 12; ++k) v[k] = make_float2(v[k].x*mk[k], v[k].y*mk[k]);
  fft384_scr<1>(v, li);                    // natural-h regs
#pragma unroll
  for (int k = 0; k < 12; ++k) drow[offmap(32*k + li)] = __float22half2_rn(v[k]);  // own column, in-order DS
  __syncthreads();

  for (int e = tid; e < NCOL*Hn; e += CTPB) {
    int wi = e & (NCOL-1), h = e >> 4;
    tmp[tbase + (size_t)h*Wn + w0 + wi] = dbuf[wi*CPITCH + offmap(h)];
  }
}

// rhs column pass: stage y*mask*(1/384), inverse column FFT; natural tmp out.
// (float2 LDS staging — the R4 half2 variant regressed; kept as measured-best.)
__global__ __launch_bounds__(CTPB) void k_col_rhs(
    const float* __restrict__ yre, const float* __restrict__ yim,
    const float* __restrict__ mask, __half2* __restrict__ tmp)
{
  __shared__ float2 dbuf[NCOL*CPITCH];
  int tid = threadIdx.x;
  int wave = tid>>6, lane = tid&63, sub = lane>>5, li = lane&31;
  int col = wave*2 + sub;
  int tile = blockIdx.x % (Wn/NCOL);
  int bc   = blockIdx.x / (Wn/NCOL);
  int b = bc / Cn;
  int w0 = tile*NCOL;
  size_t tbase = (size_t)bc*NPIX;
  size_t mbase = (size_t)b*NPIX;

  for (int e = tid; e < NCOL*Hn; e += CTPB) {
    int wi = e & (NCOL-1), h = e >> 4;
    size_t gi = (size_t)h*Wn + w0 + wi;
    float mv = mask[mbase + gi] * (1.0f/384.0f);
    dbuf[wi*CPITCH + offmap(h)] = make_float2(yre[tbase+gi]*mv, yim[tbase+gi]*mv);
  }
  __syncthreads();

  float2* drow = dbuf + col*CPITCH;
  int m = rev5(li);
  float2 v[12];
#pragma unroll
  for (int k = 0; k < 12; ++k) v[k] = drow[offmap(32*k + li)];
  fft384<1>(v, li);
  wave_fence();
#pragma unroll
  for (int k = 0; k < 12; ++k) drow[13*m + k] = v[k];
  __syncthreads();

  for (int e = tid; e < NCOL*Hn; e += CTPB) {
    int wi = e & (NCOL-1), h = e >> 4;
    tmp[tbase + (size_t)h*Wn + w0 + wi] = __float22half2_rn(dbuf[wi*CPITCH + offmap(h)]);
  }
}

// ---------------- CG tail (float4 = 2 complex) ----------------

// R5: wave butterfly reduce (6 shuffles) + one LDS slot per wave + 1 atomic.
// 2 syncthreads instead of 8.
__device__ __forceinline__ void block_reduce_atomic(float sum, float* target)
{
  __shared__ float red[TPB/64];
  for (int off = 32; off > 0; off >>= 1) sum += __shfl_down(sum, off, 64);
  int wv = threadIdx.x >> 6;
  if ((threadIdx.x & 63) == 0) red[wv] = sum;
  __syncthreads();
  if (threadIdx.x == 0) {
    float t = red[0] + red[1] + red[2] + red[3];
    unsafeAtomicAdd(target, t);
  }
  __syncthreads();
}

__global__ __launch_bounds__(TPB) void k_rhs_init(
    const float* __restrict__ xre, const float* __restrict__ xim,
    const float* __restrict__ lam, const float2* __restrict__ partial,
    float2* __restrict__ r, float2* __restrict__ p, float2* __restrict__ x,
    float* __restrict__ scal)
{
  int b = blockIdx.y;
  float l = lam[0];
  float sum = 0.0f;
  const float2* xr2 = (const float2*)(xre + (size_t)b*NPIX);
  const float2* xi2 = (const float2*)(xim + (size_t)b*NPIX);
  float4* r4 = (float4*)(r + (size_t)b*NPIX);
  float4* p4 = (float4*)(p + (size_t)b*NPIX);
  float4* x4 = (float4*)(x + (size_t)b*NPIX);
  for (int i = blockIdx.x*TPB + threadIdx.x; i < NPIX2; i += RED_BLKS*TPB) {
    float2 re = xr2[i], im = xi2[i];
    float4 rv = make_float4(l*re.x, l*im.x, l*re.y, l*im.y);
#pragma unroll
    for (int g = 0; g < GRP; ++g) {
      float4 pv = ((const float4*)(partial + ((size_t)g*Bn + b)*NPIX))[i];
      rv.x += pv.x; rv.y += pv.y; rv.z += pv.z; rv.w += pv.w;
    }
    r4[i] = rv; p4[i] = rv;
    x4[i] = make_float4(0.f, 0.f, 0.f, 0.f);
    sum += rv.x*rv.x + rv.y*rv.y + rv.z*rv.z + rv.w*rv.w;
  }
  block_reduce_atomic(sum, &scal[b]);
}

// Ap = lambda*p + sum_g partial[g]; dots pAp/ApAp/rAp -> slot[{0,4,8}+b]
__global__ __launch_bounds__(TPB) void k_combine_dot3(
    const float2* __restrict__ p, const float2* __restrict__ r,
    const float* __restrict__ lam, const float2* __restrict__ partial,
    float2* __restrict__ Ap, float* __restrict__ slot)
{
  int b = blockIdx.y;
  float l = lam[0];
  float s_pAp = 0.f, s_AA = 0.f, s_rA = 0.f;
  const float4* p4 = (const float4*)(p + (size_t)b*NPIX);
  const float4* r4 = (const float4*)(r + (size_t)b*NPIX);
  float4* A4 = (float4*)(Ap + (size_t)b*NPIX);
  for (int i = blockIdx.x*TPB + threadIdx.x; i < NPIX2; i += RED_BLKS*TPB) {
    float4 pv = p4[i];
    float4 av = make_float4(l*pv.x, l*pv.y, l*pv.z, l*pv.w);
#pragma unroll
    for (int g = 0; g < GRP; ++g) {
      float4 qv = ((const float4*)(partial + ((size_t)g*Bn + b)*NPIX))[i];
      av.x += qv.x; av.y += qv.y; av.z += qv.z; av.w += qv.w;
    }
    A4[i] = av;
    float4 rv = r4[i];
    s_pAp += pv.x*av.x + pv.y*av.y + pv.z*av.z + pv.w*av.w;
    s_AA  += av.x*av.x + av.y*av.y + av.z*av.z + av.w*av.w;
    s_rA  += rv.x*av.x + rv.y*av.y + rv.z*av.z + rv.w*av.w;
  }
  block_reduce_atomic(s_pAp, &slot[b]);
  block_reduce_atomic(s_AA,  &slot[4+b]);
  block_reduce_atomic(s_rA,  &slot[8+b]);
}

// k_scal folded in: every block recomputes alpha/beta from the reduced slots
// (4 uniform loads); block x==0 persists rTr_{it+1}.
__global__ __launch_bounds__(TPB) void k_upd(
    float2* __restrict__ x, float2* __restrict__ r, float2* __restrict__ p,
    const float2* __restrict__ Ap, float* __restrict__ scal, int it)
{
  int b = blockIdx.y;
  float rtr = scal[it*4 + b];
  const float* slot = scal + 64 + it*12;
  bool act = rtr > TOLF;
  float alpha = act ? rtr / slot[b] : 0.f;
  float rtrn = act ? fmaxf(rtr - 2.f*alpha*slot[8+b] + alpha*alpha*slot[4+b], 0.f) : rtr;
  float beta = act ? rtrn / rtr : 0.f;
  if (blockIdx.x == 0 && threadIdx.x == 0) scal[(it+1)*4 + b] = rtrn;
  if (!act) return;
  float4* x4 = (float4*)(x + (size_t)b*NPIX);
  float4* r4 = (float4*)(r + (size_t)b*NPIX);
  float4* p4 = (float4*)(p + (size_t)b*NPIX);
  const float4* A4 = (const float4*)(Ap + (size_t)b*NPIX);
  for (int i = blockIdx.x*TPB + threadIdx.x; i < NPIX2; i += RED_BLKS*TPB) {
    float4 pv = p4[i], av = A4[i], xv = x4[i], rv = r4[i];
    xv.x += alpha*pv.x; xv.y += alpha*pv.y; xv.z += alpha*pv.z; xv.w += alpha*pv.w;
    rv.x -= alpha*av.x; rv.y -= alpha*av.y; rv.z -= alpha*av.z; rv.w -= alpha*av.w;
    x4[i] = xv; r4[i] = rv;
    p4[i] = make_float4(rv.x + beta*pv.x, rv.y + beta*pv.y,
                        rv.z + beta*pv.z, rv.w + beta*pv.w);
  }
}

// ---------------- launch ----------------

extern "C" void kernel_launch(void* const* d_in, const int* in_sizes, int n_in,
                              void* d_out, int out_size, void* d_ws, size_t ws_size,
                              hipStream_t stream)
{
  const float* lam  = (const float*)d_in[0];
  const float* xre  = (const float*)d_in[1];
  const float* xim  = (const float*)d_in[2];
  const float* yre  = (const float*)d_in[3];
  const float* yim  = (const float*)d_in[4];
  const float* sre  = (const float*)d_in[5];
  const float* sim  = (const float*)d_in[6];
  const float* mask = (const float*)d_in[7];

  const size_t szTmp  = (size_t)Bn*Cn*NPIX*sizeof(__half2);   // 37.7 MB
  const size_t szVec  = (size_t)Bn*NPIX*sizeof(float2);       // 4.7 MB
  const size_t szMask = (size_t)Bn*NPIX*sizeof(float);        // 2.4 MB
  const size_t szSh   = (size_t)Bn*Cn*NPIX*sizeof(__half2);   // 37.7 MB
  const size_t base   = szTmp + (size_t)GRP*szVec + 3*szVec + 2048 + szMask;
  const bool useSh    = (ws_size >= base + szSh);  // ws_size fixed -> stable path

  char* ws = (char*)d_ws;
  __half2* tmp = (__half2*)ws;  ws += szTmp;
  float2* part = (float2*)ws;   ws += (size_t)GRP*szVec;
  float2* r    = (float2*)ws;   ws += szVec;
  float2* p    = (float2*)ws;   ws += szVec;
  float2* Ap   = (float2*)ws;   ws += szVec;
  float*  scal = (float*)ws;    ws += 2048;
  float*  mskP = (float*)ws;    ws += szMask;
  __half2* Sh  = (__half2*)ws;
  float2* x    = (float2*)d_out;

  dim3 blk(TPB);
  dim3 rg(RED_BLKS, Bn);
  int grid_row = Bn*Cn*(Hn/8);       // 3072
  int grid_col = Bn*Cn*(Wn/NCOL);    // 1536
  int grid_inv = Bn*GRP*(Hn/8);      // 768

  k_maskp<<<(Bn*NPIX)/TPB, blk, 0, stream>>>(mask, mskP, scal);
  if (useSh)
    k_spack<<<(Bn*Cn*NPIX)/TPB, blk, 0, stream>>>(sre, sim, Sh);

  // ---- rhs = AH(y) + lambda*x ----
  k_col_rhs<<<grid_col, CTPB, 0, stream>>>(yre, yim, mask, tmp);
  k_row_inv_nat<<<grid_inv, blk, 0, stream>>>(tmp, sre, sim, part);
  k_rhs_init<<<rg, blk, 0, stream>>>(xre, xim, lam, part, r, p, x, scal);

  for (int it = 0; it < NITER; ++it) {
    if (useSh) {
      k_row_fwd<true><<<grid_row, blk, 0, stream>>>(p, sre, sim, Sh, tmp);
      k_col_full<<<grid_col, CTPB, 0, stream>>>(tmp, mskP);
      k_row_inv_scr<true><<<grid_inv, blk, 0, stream>>>(tmp, sre, sim, Sh, part);
    } else {
      k_row_fwd<false><<<grid_row, blk, 0, stream>>>(p, sre, sim, Sh, tmp);
      k_col_full<<<grid_col, CTPB, 0, stream>>>(tmp, mskP);
      k_row_inv_scr<false><<<grid_inv, blk, 0, stream>>>(tmp, sre, sim, Sh, part);
    }
    k_combine_dot3<<<rg, blk, 0, stream>>>(p, r, lam, part, Ap, scal + 64 + it*12);
    k_upd<<<rg, blk, 0, stream>>>(x, r, p, Ap, scal, it);
  }
}